// Round 11
// baseline (303.663 us; speedup 1.0000x reference)
//
#include <hip/hip_runtime.h>
#include <hip/hip_bf16.h>
#include <stdint.h>

// Problem constants
#define NB 4
#define NL 2048
#define NE 1024
#define NH 16
#define ND 64
#define NM (NB*NL)   // 8192 rows

typedef float f32x4 __attribute__((ext_vector_type(4)));
typedef float f32x16 __attribute__((ext_vector_type(16)));
typedef short s16x8 __attribute__((ext_vector_type(8)));
typedef unsigned int u32x4 __attribute__((ext_vector_type(4)));

__device__ __forceinline__ unsigned short f2b(float f) {
  uint32_t u = __float_as_uint(f);
  u += 0x7fffu + ((u >> 16) & 1u);   // RNE; inputs are finite
  return (unsigned short)(u >> 16);
}

// packed pair via v_cvt_pk_bf16_f32 (compiler-lowered, m240: don't hand-write asm)
__device__ __forceinline__ uint32_t pk2(float a, float b) {
  __hip_bfloat162 h = __float22bfloat162_rn(make_float2(a, b));
  union { __hip_bfloat162 h; uint32_t u; } c; c.h = h; return c.u;
}

__device__ __forceinline__ void gload16(const void* g, void* l) {
  __builtin_amdgcn_global_load_lds((const __attribute__((address_space(1))) void*)g,
                                   (__attribute__((address_space(3))) void*)l, 16, 0, 0);
}

// ---------------- fp32 -> bf16 conversion, ALL tensors in one launch -------
// chunk ids: [0, 1048576) -> x ; then 4 x 131072 for Wq,Wk,Wv,Wo.
__global__ void cvt_all_kernel(const float* __restrict__ x,
                               const float* __restrict__ w0, const float* __restrict__ w1,
                               const float* __restrict__ w2, const float* __restrict__ w3,
                               unsigned short* __restrict__ xb,
                               unsigned short* __restrict__ o0, unsigned short* __restrict__ o1,
                               unsigned short* __restrict__ o2, unsigned short* __restrict__ o3) {
  const int NX = (NM * NE) / 8;          // 1048576
  const int NW = (NE * NE) / 8;          // 131072
  int stride = gridDim.x * blockDim.x;
  for (int i = blockIdx.x * blockDim.x + threadIdx.x; i < NX + 4 * NW; i += stride) {
    const float* in; unsigned short* out; int off;
    if (i < NX) { in = x; out = xb; off = i; }
    else {
      int j = i - NX;
      int s = j >> 17;
      off = j & (NW - 1);
      in  = (s == 0) ? w0 : (s == 1) ? w1 : (s == 2) ? w2 : w3;
      out = (s == 0) ? o0 : (s == 1) ? o1 : (s == 2) ? o2 : o3;
    }
    const float4* p = (const float4*)in + (size_t)off * 2;
    float4 a = p[0], b = p[1];
    uint4 r;
    r.x = pk2(a.x, a.y); r.y = pk2(a.z, a.w);
    r.z = pk2(b.x, b.y); r.w = pk2(b.z, b.w);
    *((uint4*)out + off) = r;
  }
}

// ---------------- B^T-input bf16 GEMM, 128x128 tile, BK=64 -----------------
// C[m][n] = sum_k A[m][k]*W[n][k] + bias[n]
// MODE 0: fused QKV projection. blockIdx.x: 0-7 -> Q, 8-15 -> K, 16-23 -> V.
//         Q,K written [B,H,L,64] bf16 (Q pre-scaled by 0.125*log2e);
//         V written transposed [B,H,64,L] bf16.
// MODE 1: output projection, fp32 out [M][NE] + bias.
// No __launch_bounds__: m97-style, let regalloc pick (A/B vs (256,2)).
template<int MODE>
__global__ void gemm_bt(const unsigned short* __restrict__ A,
                        const unsigned short* __restrict__ W0,
                        const unsigned short* __restrict__ W1,
                        const unsigned short* __restrict__ W2,
                        const float* __restrict__ b0,
                        const float* __restrict__ b1,
                        const float* __restrict__ b2,
                        unsigned short* __restrict__ O0,
                        unsigned short* __restrict__ O1,
                        unsigned short* __restrict__ O2,
                        float* __restrict__ fout)
{
  __shared__ alignas(16) char smem[32768];
  char* sA = smem;            // [128][64] bf16, XOR-swizzled
  char* sB = smem + 16384;    // [128][64] bf16, XOR-swizzled

  const int tid = threadIdx.x;
  const int lane = tid & 63;
  const int wid = tid >> 6;
  const int bx = blockIdx.x, by = blockIdx.y;
  const int m0 = by * 128;

  int which = 0;
  const unsigned short* Wsel;
  const float* bias;
  int n0;
  if (MODE == 0) {
    which = bx >> 3;
    Wsel = (which == 0) ? W0 : ((which == 1) ? W1 : W2);
    bias = (which == 0) ? b0 : ((which == 1) ? b1 : b2);
    n0 = (bx & 7) * 128;
  } else {
    Wsel = W0; bias = b0; n0 = bx * 128;
  }

  const int wr = (wid >> 1) * 64;
  const int wc = (wid & 1) * 64;
  int aaddr[4], baddr[4];
#pragma unroll
  for (int m = 0; m < 4; ++m) {
    int ra = wr + m * 16 + (lane & 15);
    aaddr[m] = ra * 128 + (((lane >> 4) * 16) ^ ((ra & 7) << 4));
    int rb = wc + m * 16 + (lane & 15);
    baddr[m] = rb * 128 + (((lane >> 4) * 16) ^ ((rb & 7) << 4));
  }

  f32x4 acc[4][4] = {};
  const int c0 = wid * 64 + lane;

  for (int kt = 0; kt < 16; ++kt) {
    const int k0 = kt * 64;
#pragma unroll
    for (int it = 0; it < 4; ++it) {
      int c = it * 256 + c0;              // 16B chunk id, dest byte = c*16
      int row = c >> 3;                   // 128B per row
      int sb = ((((c & 7) << 4)) ^ ((row & 7) << 4)) >> 1;  // inverse-swizzled src elem
      gload16(A    + (size_t)(m0 + row) * NE + k0 + sb, sA + it * 4096 + wid * 1024);
      gload16(Wsel + (size_t)(n0 + row) * NE + k0 + sb, sB + it * 4096 + wid * 1024);
    }
    __syncthreads();
#pragma unroll
    for (int kk = 0; kk < 2; ++kk) {
      s16x8 af[4], bf[4];
#pragma unroll
      for (int m = 0; m < 4; ++m) af[m] = *(const s16x8*)(sA + (aaddr[m] ^ (kk << 6)));
#pragma unroll
      for (int n = 0; n < 4; ++n) bf[n] = *(const s16x8*)(sB + (baddr[n] ^ (kk << 6)));
#pragma unroll
      for (int m = 0; m < 4; ++m)
#pragma unroll
        for (int n = 0; n < 4; ++n)
          acc[m][n] = __builtin_amdgcn_mfma_f32_16x16x32_bf16(af[m], bf[n], acc[m][n], 0, 0, 0);
    }
    __syncthreads();
  }

  // Epilogue. C/D layout: col = lane&15, row = (lane>>4)*4 + reg (m89/m91).
  // Q (which==0) pre-scaled by attn scale*log2e so attn uses exp2 directly.
  const float qsc = (MODE == 0 && ((bx >> 3) == 0)) ? 0.18033688011112042f : 1.0f;
#pragma unroll
  for (int m = 0; m < 4; ++m) {
    const int row0 = m0 + wr + m * 16 + ((lane >> 4) << 2);
#pragma unroll
    for (int n = 0; n < 4; ++n) {
      const int col = n0 + wc + n * 16 + (lane & 15);
      const float bv = bias[col];
      if (MODE == 1) {
#pragma unroll
        for (int r = 0; r < 4; ++r)
          fout[(size_t)(row0 + r) * NE + col] = acc[m][n][r] + bv;
      } else {
        const int b = row0 >> 11;
        const int l = row0 & 2047;
        const int h = col >> 6;
        const int d = col & 63;
        if (which < 2) {
          unsigned short* dst = (which == 0) ? O0 : O1;
#pragma unroll
          for (int r = 0; r < 4; ++r)
            dst[((size_t)(b * NH + h) * NL + (l + r)) * ND + d] = f2b((acc[m][n][r] + bv) * qsc);
        } else {
          // V transposed: [B,H,64,L]; 4 regs are 4 consecutive l -> pack 8B store
          uint2 w;
          w.x = pk2(acc[m][n][0] + bv, acc[m][n][1] + bv);
          w.y = pk2(acc[m][n][2] + bv, acc[m][n][3] + bv);
          *(uint2*)(O2 + ((size_t)(b * NH + h) * ND + d) * NL + l) = w;
        }
      }
    }
  }
}

// ---------------- flash attention fwd, per (b,h), q-tile 128 ----------------
// Q (pre-scaled), K: [B,H,L,64] bf16; Vt: [B,H,64,L] bf16; AO out: [B,L,E] bf16.
// 32x32x16 MFMA structure: lane owns q = lane&31; row data split only across
// the lane^32 partner -> in-register P via shfl_xor(32)+select (HW-proven r6).
// kv-tile 64, double-buffered K/V, prefetch-before-compute (T3 2-phase).
__launch_bounds__(256, 4)
__global__ void attn_kernel(const unsigned short* __restrict__ Q,
                            const unsigned short* __restrict__ K,
                            const unsigned short* __restrict__ Vt,
                            unsigned short* __restrict__ AO)
{
  __shared__ alignas(16) char smem[32768];
  // [0,8K)+[8K,16K): sK dbuf [64 kv][64 d]  swizzled
  // [16K,24K)+[24K,32K): sV dbuf [64 d][64 kv] swizzled

  const int tid = threadIdx.x;
  const int lane = tid & 63;
  const int wid = tid >> 6;
  const int ql = lane & 31;     // q-row within wave tile (also kv/d row for frags)
  const int hh = lane >> 5;     // half-select (0/1)
  const int qt = blockIdx.x;
  const int bh = blockIdx.y;
  const int b = bh >> 4;
  const int h = bh & 15;
  const size_t base = (size_t)bh * NL * ND;
  const int q0 = qt * 128 + wid * 32;     // this wave's 32 q rows

  // Q fragments (B-role of 32x32x16): lane holds Q[q0+ql][ks*16 + hh*8 + j]
  s16x8 qf[4];
#pragma unroll
  for (int ks = 0; ks < 4; ++ks)
    qf[ks] = *(const s16x8*)(Q + base + (size_t)(q0 + ql) * ND + ks * 16 + hh * 8);

  // fragment LDS byte offsets (same geometry for sK and sV: [64 rows][128B])
  int fa[2][4];
#pragma unroll
  for (int t = 0; t < 2; ++t)
#pragma unroll
    for (int ks = 0; ks < 4; ++ks) {
      int r = t * 32 + ql;
      fa[t][ks] = r * 128 + ((ks * 32 + hh * 16) ^ ((r & 7) << 4));
    }

  // staging: per-lane global base pointers + LDS offsets, hoisted out of loop
  const unsigned short* gK[2];
  const unsigned short* gV[2];
  int ldsOff[2];
#pragma unroll
  for (int it = 0; it < 2; ++it) {
    int c = it * 256 + wid * 64 + lane;
    int row = c >> 3;
    int sb = (((c & 7) << 4) ^ ((row & 7) << 4)) >> 1;
    gK[it] = K  + base + (size_t)row * ND + sb;   // + t*4096 per kv-tile
    gV[it] = Vt + base + (size_t)row * NL + sb;   // + t*64   per kv-tile
    ldsOff[it] = it * 4096 + wid * 1024;
  }

  f32x16 o0 = {}, o1 = {};      // O^T acc: d = td*32 + 4*hh + (reg&3) + 8*(reg>>2), q = ql
  float rm = -1e30f, rl = 0.f;

#define STAGE(T, BUF)                                                          \
  do {                                                                         \
    _Pragma("unroll")                                                          \
    for (int it = 0; it < 2; ++it) {                                           \
      gload16(gK[it] + (T) * 4096, smem + (BUF) * 8192 + ldsOff[it]);          \
      gload16(gV[it] + (T) * 64,   smem + 16384 + (BUF) * 8192 + ldsOff[it]);  \
    }                                                                          \
  } while (0)

  STAGE(0, 0);
  __syncthreads();

  for (int t = 0; t < 32; ++t) {
    const int cur = t & 1;
    if (t < 31) STAGE(t + 1, cur ^ 1);
    const char* sKb = smem + cur * 8192;
    const char* sVb = smem + 16384 + cur * 8192;

    // S^T = K Q^T (two 32-kv halves). s*[reg] = S[q=ql][kv = t32*32+4hh+(reg&3)+8(reg>>2)]
    f32x16 s0 = {}, s1 = {};
    __builtin_amdgcn_s_setprio(1);
#pragma unroll
    for (int ks = 0; ks < 4; ++ks) {
      s16x8 kf0 = *(const s16x8*)(sKb + fa[0][ks]);
      s16x8 kf1 = *(const s16x8*)(sKb + fa[1][ks]);
      s0 = __builtin_amdgcn_mfma_f32_32x32x16_bf16(kf0, qf[ks], s0, 0, 0, 0);
      s1 = __builtin_amdgcn_mfma_f32_32x32x16_bf16(kf1, qf[ks], s1, 0, 0, 0);
    }
    __builtin_amdgcn_s_setprio(0);

    // row max: in-lane tree (32 vals) + partner via shfl (HW-proven)
    float q0m = fmaxf(fmaxf(s0[0], s0[1]), fmaxf(s0[2], s0[3]));
    float q1m = fmaxf(fmaxf(s0[4], s0[5]), fmaxf(s0[6], s0[7]));
    float q2m = fmaxf(fmaxf(s0[8], s0[9]), fmaxf(s0[10], s0[11]));
    float q3m = fmaxf(fmaxf(s0[12], s0[13]), fmaxf(s0[14], s0[15]));
    float q4m = fmaxf(fmaxf(s1[0], s1[1]), fmaxf(s1[2], s1[3]));
    float q5m = fmaxf(fmaxf(s1[4], s1[5]), fmaxf(s1[6], s1[7]));
    float q6m = fmaxf(fmaxf(s1[8], s1[9]), fmaxf(s1[10], s1[11]));
    float q7m = fmaxf(fmaxf(s1[12], s1[13]), fmaxf(s1[14], s1[15]));
    float pm = fmaxf(fmaxf(fmaxf(q0m, q1m), fmaxf(q2m, q3m)),
                     fmaxf(fmaxf(q4m, q5m), fmaxf(q6m, q7m)));
    pm = fmaxf(pm, __shfl_xor(pm, 32));

    float mn = rm;
    if (!__all(pm - mn <= 8.0f)) {      // T13 defer-max
      mn = fmaxf(mn, pm);
      float al = __builtin_amdgcn_exp2f(rm - mn);
      rl *= al;
      o0 = o0 * al;
      o1 = o1 * al;
      rm = mn;
    }

    // exp + pack to bf16 pairs. w[t][i] = pk2(p[2i], p[2i+1])
    uint32_t w0[8], w1[8];
    float ts0 = 0.f, ts1 = 0.f, ts2 = 0.f, ts3 = 0.f;
#pragma unroll
    for (int i = 0; i < 8; ++i) {
      float e0 = __builtin_amdgcn_exp2f(s0[2 * i]     - mn);
      float e1 = __builtin_amdgcn_exp2f(s0[2 * i + 1] - mn);
      float e2 = __builtin_amdgcn_exp2f(s1[2 * i]     - mn);
      float e3 = __builtin_amdgcn_exp2f(s1[2 * i + 1] - mn);
      ts0 += e0; ts1 += e1; ts2 += e2; ts3 += e3;
      w0[i] = pk2(e0, e1);
      w1[i] = pk2(e2, e3);
    }
    float ts = (ts0 + ts1) + (ts2 + ts3);
    ts += __shfl_xor(ts, 32);
    rl += ts;

    // in-register P exchange across lane^32 (shfl+select form, HW-proven r6).
    // pfr[ks] element j = P[q=ql][kv = ks*16 + hh*8 + j]
    s16x8 pfr[4];
#pragma unroll
    for (int tt = 0; tt < 2; ++tt) {
      const uint32_t* w = tt ? w1 : w0;
      u32x4 lo, hi;   // lo -> pfr[2tt], hi -> pfr[2tt+1]
#pragma unroll
      for (int aa = 0; aa < 2; ++aa) {            // low ks of this half
        uint32_t v  = hh ? w[aa] : w[aa + 2];
        uint32_t sv = (uint32_t)__shfl_xor((int)v, 32);
        lo[aa]     = hh ? sv        : w[aa];
        lo[aa + 2] = hh ? w[aa + 2] : sv;
      }
#pragma unroll
      for (int aa = 0; aa < 2; ++aa) {            // high ks of this half
        uint32_t v  = hh ? w[aa + 4] : w[aa + 6];
        uint32_t sv = (uint32_t)__shfl_xor((int)v, 32);
        hi[aa]     = hh ? sv        : w[aa + 4];
        hi[aa + 2] = hh ? w[aa + 6] : sv;
      }
      pfr[2 * tt]     = __builtin_bit_cast(s16x8, lo);
      pfr[2 * tt + 1] = __builtin_bit_cast(s16x8, hi);
    }

    // O^T += V^T P^T
    __builtin_amdgcn_s_setprio(1);
#pragma unroll
    for (int ks = 0; ks < 4; ++ks) {
      s16x8 vf0 = *(const s16x8*)(sVb + fa[0][ks]);
      s16x8 vf1 = *(const s16x8*)(sVb + fa[1][ks]);
      o0 = __builtin_amdgcn_mfma_f32_32x32x16_bf16(vf0, pfr[ks], o0, 0, 0, 0);
      o1 = __builtin_amdgcn_mfma_f32_32x32x16_bf16(vf1, pfr[ks], o1, 0, 0, 0);
    }
    __builtin_amdgcn_s_setprio(0);
    __syncthreads();
  }
#undef STAGE

  // normalize + write [B,L,E] bf16 (8B packed stores)
  const float inv = 1.0f / rl;
  const size_t orow = (size_t)(b * NL + q0 + ql) * NE + h * 64;
#pragma unroll
  for (int q4 = 0; q4 < 4; ++q4) {
    uint2 wv;
    wv.x = pk2(o0[4 * q4] * inv, o0[4 * q4 + 1] * inv);
    wv.y = pk2(o0[4 * q4 + 2] * inv, o0[4 * q4 + 3] * inv);
    *(uint2*)(AO + orow + 4 * hh + 8 * q4) = wv;
  }
#pragma unroll
  for (int q4 = 0; q4 < 4; ++q4) {
    uint2 wv;
    wv.x = pk2(o1[4 * q4] * inv, o1[4 * q4 + 1] * inv);
    wv.y = pk2(o1[4 * q4 + 2] * inv, o1[4 * q4 + 3] * inv);
    *(uint2*)(AO + orow + 32 + 4 * hh + 8 * q4) = wv;
  }
}

// ---------------------------------------------------------------------------
extern "C" void kernel_launch(void* const* d_in, const int* in_sizes, int n_in,
                              void* d_out, int out_size, void* d_ws, size_t ws_size,
                              hipStream_t stream) {
  const float* x  = (const float*)d_in[0];
  const float* Wq = (const float*)d_in[1];
  const float* bq = (const float*)d_in[2];
  const float* Wk = (const float*)d_in[3];
  const float* bk = (const float*)d_in[4];
  const float* Wv = (const float*)d_in[5];
  const float* bv = (const float*)d_in[6];
  const float* Wo = (const float*)d_in[7];
  const float* bo = (const float*)d_in[8];
  float* out = (float*)d_out;
  char* ws = (char*)d_ws;

  // Workspace layout (72 MB):
  //   [ 0,16) MB : xb  (x bf16)      -- dead after gemm<0>; reused as AOw
  //   [16,18) MB : wqb   [18,20): wkb   [20,22): wvb   [22,24): wob
  //   [24,40) MB : Qw [B,H,L,64] (pre-scaled)
  //   [40,56) MB : Kw [B,H,L,64]
  //   [56,72) MB : Vtw [B,H,64,L]
  unsigned short* xb  = (unsigned short*)(ws);
  unsigned short* AOw = (unsigned short*)(ws);                      // aliases xb
  unsigned short* wqb = (unsigned short*)(ws + (16u << 20));
  unsigned short* wkb = (unsigned short*)(ws + (18u << 20));
  unsigned short* wvb = (unsigned short*)(ws + (20u << 20));
  unsigned short* wob = (unsigned short*)(ws + (22u << 20));
  unsigned short* Qw  = (unsigned short*)(ws + (24u << 20));
  unsigned short* Kw  = (unsigned short*)(ws + (40u << 20));
  unsigned short* Vtw = (unsigned short*)(ws + (56u << 20));
  (void)in_sizes; (void)n_in; (void)out_size; (void)ws_size;

  cvt_all_kernel<<<2048, 256, 0, stream>>>(x, Wq, Wk, Wv, Wo,
                                           xb, wqb, wkb, wvb, wob);

  gemm_bt<0><<<dim3(24, 64), 256, 0, stream>>>(xb, wqb, wkb, wvb, bq, bk, bv,
                                               Qw, Kw, Vtw, nullptr);
  attn_kernel<<<dim3(16, 64), 256, 0, stream>>>(Qw, Kw, Vtw, AOw);
  gemm_bt<1><<<dim3(8, 64), 256, 0, stream>>>(AOw, wob, nullptr, nullptr, bo,
                                              nullptr, nullptr,
                                              nullptr, nullptr, nullptr, out);
}